// Round 2
// baseline (692.435 us; speedup 1.0000x reference)
//
#include <hip/hip_runtime.h>
#include <hip/hip_bf16.h>
#include <stdint.h>

#define T_TOK 8192
#define D_EMB 1024
#define H_DIM 2048
#define N1 4096
#define NE 8

typedef __bf16 bf16_t;
typedef __bf16 bf16x8 __attribute__((ext_vector_type(8)));
typedef __bf16 bf16x4 __attribute__((ext_vector_type(4)));
typedef float f32x4 __attribute__((ext_vector_type(4)));

typedef __attribute__((address_space(1))) void gvoid_t;
typedef __attribute__((address_space(3))) void svoid_t;

__device__ __forceinline__ void gld_lds16(bf16_t* lds, const bf16_t* g) {
  __builtin_amdgcn_global_load_lds((gvoid_t*)g, (svoid_t*)lds, 16, 0, 0);
}

// ---------------- x fp32 -> bf16 ----------------
__global__ __launch_bounds__(256) void k_cvt_x(const float* __restrict__ x,
                                               bf16_t* __restrict__ xb) {
  int i = blockIdx.x * 256 + threadIdx.x;  // 1048576 threads, 8 elems each
  const float4* p = (const float4*)x;
  float4 a = p[i * 2], b = p[i * 2 + 1];
  bf16x8 o;
  o[0] = (bf16_t)a.x; o[1] = (bf16_t)a.y; o[2] = (bf16_t)a.z; o[3] = (bf16_t)a.w;
  o[4] = (bf16_t)b.x; o[5] = (bf16_t)b.y; o[6] = (bf16_t)b.z; o[7] = (bf16_t)b.w;
  *(bf16x8*)(xb + (size_t)i * 8) = o;
}

// ------- weight convert: [E][K][N] fp32 -> [E][N'][K] bf16 (transpose, opt interleave) -------
template <bool ILV>
__global__ __launch_bounds__(256) void k_cvt_w(const float* __restrict__ src,
                                               bf16_t* __restrict__ dst, int K, int N) {
  __shared__ float tile[32][33];
  int e = blockIdx.z;
  int k0 = blockIdx.y << 5, j0 = blockIdx.x << 5;
  const float* s = src + (size_t)e * K * N;
  bf16_t* d = dst + (size_t)e * K * N;
  int t = threadIdx.x;
  int col = t & 31, r0 = t >> 5;
#pragma unroll
  for (int i = 0; i < 4; i++)
    tile[r0 + i * 8][col] = s[(size_t)(k0 + r0 + i * 8) * N + j0 + col];
  __syncthreads();
  int jj = t >> 3, kk0 = (t & 7) << 2;
  int j = j0 + jj, np_;
  if (ILV) {
    int half = N >> 1;
    if (j < half) np_ = ((j >> 4) << 5) | (j & 15);
    else { int jm = j - half; np_ = ((jm >> 4) << 5) | 16 | (jm & 15); }
  } else np_ = j;
  bf16x4 o;
  o[0] = (bf16_t)tile[kk0][jj];     o[1] = (bf16_t)tile[kk0 + 1][jj];
  o[2] = (bf16_t)tile[kk0 + 2][jj]; o[3] = (bf16_t)tile[kk0 + 3][jj];
  *(bf16x4*)(d + (size_t)np_ * K + k0 + kk0) = o;
}

// ---------------- router: scores = x @ wg, top-2, softmax, counts ----------------
__global__ __launch_bounds__(256) void k_router(const float* __restrict__ x,
                                                const float* __restrict__ wg,
                                                int* __restrict__ counts,
                                                int* __restrict__ tki,
                                                float* __restrict__ tkp) {
  __shared__ float wgl[NE * D_EMB];  // transposed [e][d]
  int t = threadIdx.x;
  for (int i = t; i < NE * D_EMB; i += 256) {
    int dd = i >> 3, ee = i & 7;
    wgl[ee * D_EMB + dd] = wg[i];
  }
  __syncthreads();
  int wave = t >> 6, lane = t & 63;
  int tok = (blockIdx.x << 2) + wave;
  const float* xr = x + (size_t)tok * D_EMB;
  float acc[NE] = {};
  for (int d = lane; d < D_EMB; d += 64) {
    float xv = xr[d];
#pragma unroll
    for (int e = 0; e < NE; e++) acc[e] += xv * wgl[e * D_EMB + d];
  }
#pragma unroll
  for (int e = 0; e < NE; e++) {
#pragma unroll
    for (int off = 32; off; off >>= 1) acc[e] += __shfl_xor(acc[e], off);
  }
  if (lane == 0) {
    int i0 = 0; float s0 = acc[0];
#pragma unroll
    for (int e = 1; e < NE; e++) if (acc[e] > s0) { s0 = acc[e]; i0 = e; }
    int i1 = -1; float s1 = -3.4e38f;
#pragma unroll
    for (int e = 0; e < NE; e++) if (e != i0 && acc[e] > s1) { s1 = acc[e]; i1 = e; }
    float ex = __expf(s1 - s0);
    float inv = 1.f / (1.f + ex);
    tki[tok * 2] = i0; tki[tok * 2 + 1] = i1;
    tkp[tok * 2] = inv; tkp[tok * 2 + 1] = ex * inv;
    atomicAdd(&counts[i0], 1); atomicAdd(&counts[i1], 1);
  }
}

__global__ void k_offsets(const int* __restrict__ counts, int* __restrict__ offsets) {
  if (threadIdx.x == 0) {
    int s = 0;
#pragma unroll
    for (int e = 0; e < NE; e++) { offsets[e] = s; s += counts[e]; }
    offsets[NE] = s;
  }
}

__global__ __launch_bounds__(256) void k_scatter(const int* __restrict__ tki,
                                                 const float* __restrict__ tkp,
                                                 const int* __restrict__ offsets,
                                                 int* __restrict__ fill,
                                                 int* __restrict__ tlist,
                                                 float* __restrict__ plist,
                                                 int* __restrict__ tok2pos) {
  int tok = blockIdx.x * 256 + threadIdx.x;
  if (tok >= T_TOK) return;
#pragma unroll
  for (int k = 0; k < 2; k++) {
    int e = tki[tok * 2 + k];
    int pos = offsets[e] + atomicAdd(&fill[e], 1);
    tlist[pos] = tok;
    plist[pos] = tkp[tok * 2 + k];
    tok2pos[tok * 2 + k] = pos;
  }
}

// ---------------- grouped GEMM, 128x128 tile, BK=32, 4 waves (2x2), 16x16x32 bf16 MFMA ----
// PHASE 1: A = xb gathered by tlist [.,1024]; B = w12b[e] [4096][1024]; SwiGLU -> hb
// PHASE 2: A = hb contiguous [.,2048];       B = w3b[e]  [1024][2048]; -> partial (fp32)
template <int PHASE>
__global__ __launch_bounds__(256) void k_gemm(const bf16_t* __restrict__ A,
                                              const bf16_t* __restrict__ B,
                                              const int* __restrict__ offsets,
                                              const int* __restrict__ tlist,
                                              bf16_t* __restrict__ hb,
                                              float* __restrict__ partial) {
  constexpr int AK = (PHASE == 1) ? D_EMB : H_DIM;
  const int e = blockIdx.z;
  const int seg = offsets[e];
  const int cnt = offsets[e + 1] - seg;
  const int mt = blockIdx.y;
  if (mt * 128 >= cnt) return;
  const int n0 = blockIdx.x << 7;
  const bf16_t* Bexp = B + (size_t)e * (size_t)AK * ((PHASE == 1) ? N1 : D_EMB);

  __shared__ bf16_t As[128 * 32];
  __shared__ bf16_t Bs[128 * 32];

  const int tid = threadIdx.x;
  const int wave = tid >> 6, lane = tid & 63;

  const bf16_t* a_src[2];
  const bf16_t* b_src[2];
#pragma unroll
  for (int i = 0; i < 2; i++) {
    int o = i * 4096 + wave * 1024 + lane * 16;  // byte offset in 8KB tile
    int r = o >> 6;                              // row (64B = 32 bf16 per row)
    int kc = (o >> 4) & 3;                       // 16B chunk within row
    int rb = mt * 128 + r;
    if (PHASE == 1) {
      int tok = (rb < cnt) ? tlist[seg + rb] : tlist[seg];
      a_src[i] = A + (size_t)tok * AK + kc * 8;
    } else {
      int rowg = (rb < cnt) ? (seg + rb) : seg;
      a_src[i] = A + (size_t)rowg * AK + kc * 8;
    }
    b_src[i] = Bexp + (size_t)(n0 + r) * AK + kc * 8;
  }

  const int wr = wave >> 1, wc = wave & 1;
  const int fr = lane & 15;
  const int fk = (lane >> 4) << 3;

  f32x4 acc[4][4] = {};

  for (int k0 = 0; k0 < AK; k0 += 32) {
    __syncthreads();
#pragma unroll
    for (int i = 0; i < 2; i++) gld_lds16(&As[i * 2048 + wave * 512], a_src[i] + k0);
#pragma unroll
    for (int i = 0; i < 2; i++) gld_lds16(&Bs[i * 2048 + wave * 512], b_src[i] + k0);
    __syncthreads();
#pragma unroll
    for (int mf = 0; mf < 4; mf++) {
      bf16x8 af = *(const bf16x8*)&As[(wr * 64 + mf * 16 + fr) * 32 + fk];
#pragma unroll
      for (int nf = 0; nf < 4; nf++) {
        bf16x8 bfv = *(const bf16x8*)&Bs[(wc * 64 + nf * 16 + fr) * 32 + fk];
        acc[mf][nf] = __builtin_amdgcn_mfma_f32_16x16x32_bf16(af, bfv, acc[mf][nf], 0, 0, 0);
      }
    }
  }

  if (PHASE == 1) {
#pragma unroll
    for (int mf = 0; mf < 4; mf++) {
      int rbase = mt * 128 + wr * 64 + mf * 16 + ((lane >> 4) << 2);
#pragma unroll
      for (int p = 0; p < 2; p++) {
        int hcol = (n0 >> 1) + wc * 32 + p * 16 + fr;
#pragma unroll
        for (int j = 0; j < 4; j++) {
          int r = rbase + j;
          if (r < cnt) {
            float g = acc[mf][2 * p][j];
            float v = acc[mf][2 * p + 1][j];
            float s = g / (1.f + __expf(-g));
            hb[(size_t)(seg + r) * H_DIM + hcol] = (bf16_t)(s * v);
          }
        }
      }
    }
  } else {
#pragma unroll
    for (int mf = 0; mf < 4; mf++) {
      int rbase = mt * 128 + wr * 64 + mf * 16 + ((lane >> 4) << 2);
#pragma unroll
      for (int j = 0; j < 4; j++) {
        int r = rbase + j;
        if (r < cnt) {
          float* op = partial + (size_t)(seg + r) * D_EMB + n0 + wc * 64 + fr;
#pragma unroll
          for (int nf = 0; nf < 4; nf++) op[nf * 16] = acc[mf][nf][j];
        }
      }
    }
  }
}

// ---------------- combine: out[tok] = p0*partial[pos0] + p1*partial[pos1] ----------------
__global__ __launch_bounds__(256) void k_combine(const float* __restrict__ partial,
                                                 const float* __restrict__ tkp,
                                                 const int* __restrict__ tok2pos,
                                                 float* __restrict__ out) {
  int i = blockIdx.x * 256 + threadIdx.x;  // over T_TOK * 256 float4s
  int tok = i >> 8;
  int c4 = i & 255;
  int p0 = tok2pos[tok * 2], p1 = tok2pos[tok * 2 + 1];
  float w0 = tkp[tok * 2], w1 = tkp[tok * 2 + 1];
  const float4* r0 = (const float4*)(partial + (size_t)p0 * D_EMB);
  const float4* r1 = (const float4*)(partial + (size_t)p1 * D_EMB);
  float4 a = r0[c4], b = r1[c4];
  float4 o;
  o.x = w0 * a.x + w1 * b.x;
  o.y = w0 * a.y + w1 * b.y;
  o.z = w0 * a.z + w1 * b.z;
  o.w = w0 * a.w + w1 * b.w;
  ((float4*)out)[i] = o;
}

extern "C" void kernel_launch(void* const* d_in, const int* in_sizes, int n_in,
                              void* d_out, int out_size, void* d_ws, size_t ws_size,
                              hipStream_t stream) {
  (void)in_sizes; (void)n_in; (void)ws_size; (void)out_size;
  const float* x   = (const float*)d_in[0];
  const float* w12 = (const float*)d_in[1];
  const float* w3  = (const float*)d_in[2];
  const float* wg  = (const float*)d_in[3];
  float* out = (float*)d_out;
  char* ws = (char*)d_ws;

  const size_t OFF_XB   = 0;                       // xb: 16 MiB
  const size_t OFF_W12B = 16777216;                // w12b: 64 MiB
  const size_t OFF_W3B  = OFF_W12B + 67108864;     // w3b: 32 MiB
  const size_t OFF_HB   = OFF_W3B + 33554432;      // hb: 64 MiB
  const size_t OFF_META = OFF_HB + 67108864;
  // partial (fp32, 16384x1024 = 64 MiB) overlaps [xb|w12b] (80 MiB) — both dead
  // by the time gemm2 runs; every call regenerates xb/w12b, so replay-safe.
  const size_t OFF_PART = 0;

  bf16_t* xb   = (bf16_t*)(ws + OFF_XB);
  bf16_t* w12b = (bf16_t*)(ws + OFF_W12B);
  bf16_t* w3b  = (bf16_t*)(ws + OFF_W3B);
  bf16_t* hb   = (bf16_t*)(ws + OFF_HB);
  float* partial = (float*)(ws + OFF_PART);
  int*   counts  = (int*)(ws + OFF_META);
  int*   fill    = (int*)(ws + OFF_META + 32);
  int*   offsets = (int*)(ws + OFF_META + 64);
  int*   tki     = (int*)(ws + OFF_META + 128);
  float* tkp     = (float*)(ws + OFF_META + 128 + 65536);
  int*   tlist   = (int*)(ws + OFF_META + 128 + 2 * 65536);
  float* plist   = (float*)(ws + OFF_META + 128 + 3 * 65536);
  int*   tok2pos = (int*)(ws + OFF_META + 128 + 4 * 65536);

  hipMemsetAsync(ws + OFF_META, 0, 64, stream);

  k_cvt_x<<<4096, 256, 0, stream>>>(x, xb);
  k_cvt_w<true ><<<dim3(128, 32, 8), 256, 0, stream>>>(w12, w12b, D_EMB, N1);
  k_cvt_w<false><<<dim3(32, 64, 8), 256, 0, stream>>>(w3, w3b, H_DIM, D_EMB);
  k_router<<<2048, 256, 0, stream>>>(x, wg, counts, tki, tkp);
  k_offsets<<<1, 64, 0, stream>>>(counts, offsets);
  k_scatter<<<32, 256, 0, stream>>>(tki, tkp, offsets, fill, tlist, plist, tok2pos);
  k_gemm<1><<<dim3(32, 64, 8), 256, 0, stream>>>(xb, w12b, offsets, tlist, hb, nullptr);
  k_gemm<2><<<dim3(8, 64, 8), 256, 0, stream>>>(hb, w3b, offsets, tlist, nullptr, partial);
  k_combine<<<T_TOK, 256, 0, stream>>>(partial, tkp, tok2pos, out);
}

// Round 3
// 677.332 us; speedup vs baseline: 1.0223x; 1.0223x over previous
//
#include <hip/hip_runtime.h>
#include <hip/hip_bf16.h>
#include <stdint.h>

#define T_TOK 8192
#define D_EMB 1024
#define H_DIM 2048
#define N1 4096
#define NE 8

typedef __bf16 bf16_t;
typedef __bf16 bf16x8 __attribute__((ext_vector_type(8)));
typedef __bf16 bf16x4 __attribute__((ext_vector_type(4)));
typedef float f32x4 __attribute__((ext_vector_type(4)));

typedef __attribute__((address_space(1))) void gvoid_t;
typedef __attribute__((address_space(3))) void svoid_t;

__device__ __forceinline__ void gld_lds16(bf16_t* lds, const bf16_t* g) {
  __builtin_amdgcn_global_load_lds((gvoid_t*)g, (svoid_t*)lds, 16, 0, 0);
}

// ---------------- x fp32 -> bf16 ----------------
__global__ __launch_bounds__(256) void k_cvt_x(const float* __restrict__ x,
                                               bf16_t* __restrict__ xb) {
  int i = blockIdx.x * 256 + threadIdx.x;
  const float4* p = (const float4*)x;
  float4 a = p[i * 2], b = p[i * 2 + 1];
  bf16x8 o;
  o[0] = (bf16_t)a.x; o[1] = (bf16_t)a.y; o[2] = (bf16_t)a.z; o[3] = (bf16_t)a.w;
  o[4] = (bf16_t)b.x; o[5] = (bf16_t)b.y; o[6] = (bf16_t)b.z; o[7] = (bf16_t)b.w;
  *(bf16x8*)(xb + (size_t)i * 8) = o;
}

// ------- weight convert: [E][K][N] fp32 -> [E][N'][K] bf16 (transpose, opt interleave) -------
template <bool ILV>
__global__ __launch_bounds__(256) void k_cvt_w(const float* __restrict__ src,
                                               bf16_t* __restrict__ dst, int K, int N) {
  __shared__ float tile[32][33];
  int e = blockIdx.z;
  int k0 = blockIdx.y << 5, j0 = blockIdx.x << 5;
  const float* s = src + (size_t)e * K * N;
  bf16_t* d = dst + (size_t)e * K * N;
  int t = threadIdx.x;
  int col = t & 31, r0 = t >> 5;
#pragma unroll
  for (int i = 0; i < 4; i++)
    tile[r0 + i * 8][col] = s[(size_t)(k0 + r0 + i * 8) * N + j0 + col];
  __syncthreads();
  int jj = t >> 3, kk0 = (t & 7) << 2;
  int j = j0 + jj, np_;
  if (ILV) {
    int half = N >> 1;
    if (j < half) np_ = ((j >> 4) << 5) | (j & 15);
    else { int jm = j - half; np_ = ((jm >> 4) << 5) | 16 | (jm & 15); }
  } else np_ = j;
  bf16x4 o;
  o[0] = (bf16_t)tile[kk0][jj];     o[1] = (bf16_t)tile[kk0 + 1][jj];
  o[2] = (bf16_t)tile[kk0 + 2][jj]; o[3] = (bf16_t)tile[kk0 + 3][jj];
  *(bf16x4*)(d + (size_t)np_ * K + k0 + kk0) = o;
}

// ---------------- router ----------------
__global__ __launch_bounds__(256) void k_router(const float* __restrict__ x,
                                                const float* __restrict__ wg,
                                                int* __restrict__ counts,
                                                int* __restrict__ tki,
                                                float* __restrict__ tkp) {
  __shared__ float wgl[NE * D_EMB];
  int t = threadIdx.x;
  for (int i = t; i < NE * D_EMB; i += 256) {
    int dd = i >> 3, ee = i & 7;
    wgl[ee * D_EMB + dd] = wg[i];
  }
  __syncthreads();
  int wave = t >> 6, lane = t & 63;
  int tok = (blockIdx.x << 2) + wave;
  const float* xr = x + (size_t)tok * D_EMB;
  float acc[NE] = {};
  for (int d = lane; d < D_EMB; d += 64) {
    float xv = xr[d];
#pragma unroll
    for (int e = 0; e < NE; e++) acc[e] += xv * wgl[e * D_EMB + d];
  }
#pragma unroll
  for (int e = 0; e < NE; e++) {
#pragma unroll
    for (int off = 32; off; off >>= 1) acc[e] += __shfl_xor(acc[e], off);
  }
  if (lane == 0) {
    int i0 = 0; float s0 = acc[0];
#pragma unroll
    for (int e = 1; e < NE; e++) if (acc[e] > s0) { s0 = acc[e]; i0 = e; }
    int i1 = -1; float s1 = -3.4e38f;
#pragma unroll
    for (int e = 0; e < NE; e++) if (e != i0 && acc[e] > s1) { s1 = acc[e]; i1 = e; }
    float ex = __expf(s1 - s0);
    float inv = 1.f / (1.f + ex);
    tki[tok * 2] = i0; tki[tok * 2 + 1] = i1;
    tkp[tok * 2] = inv; tkp[tok * 2 + 1] = ex * inv;
    atomicAdd(&counts[i0], 1); atomicAdd(&counts[i1], 1);
  }
}

__global__ void k_offsets(const int* __restrict__ counts, int* __restrict__ offsets) {
  if (threadIdx.x == 0) {
    int s = 0;
#pragma unroll
    for (int e = 0; e < NE; e++) { offsets[e] = s; s += counts[e]; }
    offsets[NE] = s;
  }
}

__global__ __launch_bounds__(256) void k_scatter(const int* __restrict__ tki,
                                                 const float* __restrict__ tkp,
                                                 const int* __restrict__ offsets,
                                                 int* __restrict__ fill,
                                                 int* __restrict__ tlist,
                                                 int* __restrict__ tok2pos) {
  int tok = blockIdx.x * 256 + threadIdx.x;
  if (tok >= T_TOK) return;
#pragma unroll
  for (int k = 0; k < 2; k++) {
    int e = tki[tok * 2 + k];
    int pos = offsets[e] + atomicAdd(&fill[e], 1);
    tlist[pos] = tok;
    tok2pos[tok * 2 + k] = pos;
  }
}

// ============ grouped GEMM, 256x256 tile, BK=64, 8 waves (2Mx4N), phase-split ============
// T2 st_16x32 swizzle (inverse-swz global src + swz ds_read), T3/T4 counted vmcnt(8)
// depth-2 pipeline, T5 setprio around MFMA clusters.
// PHASE 1: A = xb gathered by tlist [.,1024]; B = w12b[e] [4096][1024] (ILV); SwiGLU -> hb
// PHASE 2: A = hb contiguous [.,2048];       B = w3b[e]  [1024][2048];      -> partial
template <int PHASE>
__global__ __launch_bounds__(512, 2) void k_gemm8(const bf16_t* __restrict__ A,
                                                  const bf16_t* __restrict__ B,
                                                  const int* __restrict__ offsets,
                                                  const int* __restrict__ tlist,
                                                  bf16_t* __restrict__ hb,
                                                  float* __restrict__ partial) {
  constexpr int AK = (PHASE == 1) ? D_EMB : H_DIM;
  constexpr int NT = AK / 64;                        // K-tiles
  constexpr int BNT = (PHASE == 1) ? N1 : D_EMB;
  const int e = blockIdx.z;
  const int seg = offsets[e];
  const int cnt = offsets[e + 1] - seg;
  const int mt = blockIdx.y;
  if (mt * 256 >= cnt) return;
  const int n0 = blockIdx.x << 8;
  const bf16_t* Bexp = B + (size_t)e * (size_t)AK * BNT;

  __shared__ bf16_t As[2][256 * 64];   // 32 KB each buf, row stride 64 bf16 = 128 B
  __shared__ bf16_t Bs[2][256 * 64];

  const int tid = threadIdx.x;
  const int wave = tid >> 6, lane = tid & 63;
  const int wr = wave >> 2, wc = wave & 3;

  // ---- staging setup: per thread 4 A + 4 B chunks of 16 B; LDS dest linear,
  // global source carries the inverse st_16x32 swizzle (rule #21).
  const bf16_t* srcA[4];
  const bf16_t* srcB[4];
#pragma unroll
  for (int i = 0; i < 4; i++) {
    int chunk = i * 512 + tid;          // 0..2047
    int row = chunk >> 3;               // 0..255
    int cphys = (chunk & 7) * 16;       // byte col in 128B row
    int clog = cphys ^ (((row >> 2) & 1) << 5);
    int rb = mt * 256 + row;
    int rbc = (rb < cnt) ? rb : (cnt - 1);
    if (PHASE == 1) {
      int tok = tlist[seg + rbc];
      srcA[i] = A + (size_t)tok * AK + (clog >> 1);
    } else {
      srcA[i] = A + (size_t)(seg + rbc) * AK + (clog >> 1);
    }
    srcB[i] = Bexp + (size_t)(n0 + row) * AK + (clog >> 1);
  }

#define STAGE8(cur, kt)                                                        \
  {                                                                            \
    const int koff_ = (kt) * 64;                                               \
    _Pragma("unroll") for (int i_ = 0; i_ < 4; i_++)                           \
        gld_lds16(&As[cur][(i_ * 512 + wave * 64) * 8], srcA[i_] + koff_);     \
    _Pragma("unroll") for (int i_ = 0; i_ < 4; i_++)                           \
        gld_lds16(&Bs[cur][(i_ * 512 + wave * 64) * 8], srcB[i_] + koff_);     \
  }

  // ---- fragment read offsets (swizzled), ks = k-step (0/1), mf/nf = frag idx
  const int fr = lane & 15;
  const int fkb = (lane >> 4) * 16;     // byte k-chunk within 32-k step
  int aoff[2][8], boff[2][4];
#pragma unroll
  for (int ks = 0; ks < 2; ks++) {
#pragma unroll
    for (int mf = 0; mf < 8; mf++) {
      int row = wr * 128 + mf * 16 + fr;
      int cl = ks * 64 + fkb;
      aoff[ks][mf] = row * 128 + (cl ^ (((row >> 2) & 1) << 5));
    }
#pragma unroll
    for (int nf = 0; nf < 4; nf++) {
      int row = wc * 64 + nf * 16 + fr;
      int cl = ks * 64 + fkb;
      boff[ks][nf] = row * 128 + (cl ^ (((row >> 2) & 1) << 5));
    }
  }

  f32x4 acc[8][4] = {};

#define DO_MFMA16(mh, ks)                                                      \
  __builtin_amdgcn_s_setprio(1);                                               \
  _Pragma("unroll") for (int i_ = 0; i_ < 4; i_++)                             \
  _Pragma("unroll") for (int nf_ = 0; nf_ < 4; nf_++)                          \
      acc[(mh) * 4 + i_][nf_] = __builtin_amdgcn_mfma_f32_16x16x32_bf16(       \
          afr[i_], bq[nf_], acc[(mh) * 4 + i_][nf_], 0, 0, 0);                 \
  __builtin_amdgcn_s_setprio(0);

  // prologue: stage tiles 0 and 1; wait tile 0 only (counted vmcnt)
  STAGE8(0, 0);
  STAGE8(1, 1);
  asm volatile("s_waitcnt vmcnt(8)" ::: "memory");
  __builtin_amdgcn_s_barrier();

  for (int t = 0; t < NT; ++t) {
    const int cur = t & 1;
    const char* asb = (const char*)&As[cur][0];
    const char* bsb = (const char*)&Bs[cur][0];
    bf16x8 afr[4], bq[4];

    // P0: ks0, m-half 0 (+ B ks0)
#pragma unroll
    for (int nf = 0; nf < 4; nf++) bq[nf] = *(const bf16x8*)(bsb + boff[0][nf]);
#pragma unroll
    for (int i = 0; i < 4; i++) afr[i] = *(const bf16x8*)(asb + aoff[0][i]);
    DO_MFMA16(0, 0);
    __builtin_amdgcn_sched_barrier(0);

    // P1: ks0, m-half 1
#pragma unroll
    for (int i = 0; i < 4; i++) afr[i] = *(const bf16x8*)(asb + aoff[0][4 + i]);
    DO_MFMA16(1, 0);
    __builtin_amdgcn_sched_barrier(0);

    // P2: ks1, m-half 0 (+ B ks1)
#pragma unroll
    for (int nf = 0; nf < 4; nf++) bq[nf] = *(const bf16x8*)(bsb + boff[1][nf]);
#pragma unroll
    for (int i = 0; i < 4; i++) afr[i] = *(const bf16x8*)(asb + aoff[1][i]);
    DO_MFMA16(0, 1);
    __builtin_amdgcn_sched_barrier(0);

    // P3: ks1, m-half 1 — reads, then release buf[cur], prefetch t+2, MFMA, wait t+1
#pragma unroll
    for (int i = 0; i < 4; i++) afr[i] = *(const bf16x8*)(asb + aoff[1][4 + i]);
    __builtin_amdgcn_sched_barrier(0);
    asm volatile("s_waitcnt lgkmcnt(0)" ::: "memory");
    __builtin_amdgcn_s_barrier();          // all waves done reading buf[cur]
    if (t + 2 < NT) STAGE8(cur, t + 2);
    __builtin_amdgcn_sched_barrier(0);
    DO_MFMA16(1, 1);
    if (t + 2 < NT) {
      asm volatile("s_waitcnt vmcnt(8)" ::: "memory");   // tile t+1 landed
      __builtin_amdgcn_s_barrier();
    } else if (t + 1 < NT) {
      asm volatile("s_waitcnt vmcnt(0)" ::: "memory");   // last tile landed
      __builtin_amdgcn_s_barrier();
    }
    __builtin_amdgcn_sched_barrier(0);
  }

  // ---- epilogue ----
  if (PHASE == 1) {
#pragma unroll
    for (int mf = 0; mf < 8; mf++) {
      int rbase = mt * 256 + wr * 128 + mf * 16 + ((lane >> 4) << 2);
#pragma unroll
      for (int p = 0; p < 2; p++) {
        int hcol = (n0 >> 1) + wc * 32 + p * 16 + fr;
#pragma unroll
        for (int j = 0; j < 4; j++) {
          int r = rbase + j;
          if (r < cnt) {
            float g = acc[mf][2 * p][j];
            float v = acc[mf][2 * p + 1][j];
            float s = g / (1.f + __expf(-g));
            hb[(size_t)(seg + r) * H_DIM + hcol] = (bf16_t)(s * v);
          }
        }
      }
    }
  } else {
#pragma unroll
    for (int mf = 0; mf < 8; mf++) {
      int rbase = mt * 256 + wr * 128 + mf * 16 + ((lane >> 4) << 2);
#pragma unroll
      for (int j = 0; j < 4; j++) {
        int r = rbase + j;
        if (r < cnt) {
          float* op = partial + (size_t)(seg + r) * D_EMB + n0 + wc * 64 + fr;
#pragma unroll
          for (int nf = 0; nf < 4; nf++) op[nf * 16] = acc[mf][nf][j];
        }
      }
    }
  }
#undef STAGE8
#undef DO_MFMA16
}

// ---------------- combine: out[tok] = p0*partial[pos0] + p1*partial[pos1] ----------------
__global__ __launch_bounds__(256) void k_combine(const float* __restrict__ partial,
                                                 const float* __restrict__ tkp,
                                                 const int* __restrict__ tok2pos,
                                                 float* __restrict__ out) {
  int i = blockIdx.x * 256 + threadIdx.x;
  int tok = i >> 8;
  int c4 = i & 255;
  int p0 = tok2pos[tok * 2], p1 = tok2pos[tok * 2 + 1];
  float w0 = tkp[tok * 2], w1 = tkp[tok * 2 + 1];
  const float4* r0 = (const float4*)(partial + (size_t)p0 * D_EMB);
  const float4* r1 = (const float4*)(partial + (size_t)p1 * D_EMB);
  float4 a = r0[c4], b = r1[c4];
  float4 o;
  o.x = w0 * a.x + w1 * b.x;
  o.y = w0 * a.y + w1 * b.y;
  o.z = w0 * a.z + w1 * b.z;
  o.w = w0 * a.w + w1 * b.w;
  ((float4*)out)[i] = o;
}

extern "C" void kernel_launch(void* const* d_in, const int* in_sizes, int n_in,
                              void* d_out, int out_size, void* d_ws, size_t ws_size,
                              hipStream_t stream) {
  (void)in_sizes; (void)n_in; (void)ws_size; (void)out_size;
  const float* x   = (const float*)d_in[0];
  const float* w12 = (const float*)d_in[1];
  const float* w3  = (const float*)d_in[2];
  const float* wg  = (const float*)d_in[3];
  float* out = (float*)d_out;
  char* ws = (char*)d_ws;

  const size_t OFF_XB   = 0;                       // xb: 16 MiB
  const size_t OFF_W12B = 16777216;                // w12b: 64 MiB
  const size_t OFF_W3B  = OFF_W12B + 67108864;     // w3b: 32 MiB
  const size_t OFF_HB   = OFF_W3B + 33554432;      // hb: 64 MiB
  const size_t OFF_META = OFF_HB + 67108864;
  // partial (fp32 16384x1024 = 64 MiB) overlaps [xb|w12b] — dead by gemm2 time.
  const size_t OFF_PART = 0;

  bf16_t* xb   = (bf16_t*)(ws + OFF_XB);
  bf16_t* w12b = (bf16_t*)(ws + OFF_W12B);
  bf16_t* w3b  = (bf16_t*)(ws + OFF_W3B);
  bf16_t* hb   = (bf16_t*)(ws + OFF_HB);
  float* partial = (float*)(ws + OFF_PART);
  int*   counts  = (int*)(ws + OFF_META);
  int*   fill    = (int*)(ws + OFF_META + 32);
  int*   offsets = (int*)(ws + OFF_META + 64);
  int*   tki     = (int*)(ws + OFF_META + 128);
  float* tkp     = (float*)(ws + OFF_META + 128 + 65536);
  int*   tlist   = (int*)(ws + OFF_META + 128 + 2 * 65536);
  int*   tok2pos = (int*)(ws + OFF_META + 128 + 3 * 65536);

  hipMemsetAsync(ws + OFF_META, 0, 64, stream);

  k_cvt_x<<<4096, 256, 0, stream>>>(x, xb);
  k_cvt_w<true ><<<dim3(128, 32, 8), 256, 0, stream>>>(w12, w12b, D_EMB, N1);
  k_cvt_w<false><<<dim3(32, 64, 8), 256, 0, stream>>>(w3, w3b, H_DIM, D_EMB);
  k_router<<<2048, 256, 0, stream>>>(x, wg, counts, tki, tkp);
  k_offsets<<<1, 64, 0, stream>>>(counts, offsets);
  k_scatter<<<32, 256, 0, stream>>>(tki, tkp, offsets, fill, tlist, tok2pos);
  k_gemm8<1><<<dim3(16, 32, 8), 512, 0, stream>>>(xb, w12b, offsets, tlist, hb, nullptr);
  k_gemm8<2><<<dim3(4, 32, 8), 512, 0, stream>>>(hb, w3b, offsets, tlist, nullptr, partial);
  k_combine<<<T_TOK, 256, 0, stream>>>(partial, tkp, tok2pos, out);
}

// Round 4
// 665.572 us; speedup vs baseline: 1.0404x; 1.0177x over previous
//
#include <hip/hip_runtime.h>
#include <hip/hip_bf16.h>
#include <stdint.h>

#define T_TOK 8192
#define D_EMB 1024
#define H_DIM 2048
#define N1 4096
#define NE 8

typedef __bf16 bf16_t;
typedef __bf16 bf16x8 __attribute__((ext_vector_type(8)));
typedef __bf16 bf16x4 __attribute__((ext_vector_type(4)));
typedef float f32x4 __attribute__((ext_vector_type(4)));

typedef __attribute__((address_space(1))) void gvoid_t;
typedef __attribute__((address_space(3))) void svoid_t;

__device__ __forceinline__ void gld_lds16(bf16_t* lds, const bf16_t* g) {
  __builtin_amdgcn_global_load_lds((gvoid_t*)g, (svoid_t*)lds, 16, 0, 0);
}

// ---------------- x fp32 -> bf16 ----------------
__global__ __launch_bounds__(256) void k_cvt_x(const float* __restrict__ x,
                                               bf16_t* __restrict__ xb) {
  int i = blockIdx.x * 256 + threadIdx.x;
  const float4* p = (const float4*)x;
  float4 a = p[i * 2], b = p[i * 2 + 1];
  bf16x8 o;
  o[0] = (bf16_t)a.x; o[1] = (bf16_t)a.y; o[2] = (bf16_t)a.z; o[3] = (bf16_t)a.w;
  o[4] = (bf16_t)b.x; o[5] = (bf16_t)b.y; o[6] = (bf16_t)b.z; o[7] = (bf16_t)b.w;
  *(bf16x8*)(xb + (size_t)i * 8) = o;
}

// ------- weight convert: [E][K][N] fp32 -> [E][N'][K] bf16 (transpose, opt interleave) -------
template <bool ILV>
__global__ __launch_bounds__(256) void k_cvt_w(const float* __restrict__ src,
                                               bf16_t* __restrict__ dst, int K, int N) {
  __shared__ float tile[32][33];
  int e = blockIdx.z;
  int k0 = blockIdx.y << 5, j0 = blockIdx.x << 5;
  const float* s = src + (size_t)e * K * N;
  bf16_t* d = dst + (size_t)e * K * N;
  int t = threadIdx.x;
  int col = t & 31, r0 = t >> 5;
#pragma unroll
  for (int i = 0; i < 4; i++)
    tile[r0 + i * 8][col] = s[(size_t)(k0 + r0 + i * 8) * N + j0 + col];
  __syncthreads();
  int jj = t >> 3, kk0 = (t & 7) << 2;
  int j = j0 + jj, np_;
  if (ILV) {
    int half = N >> 1;
    if (j < half) np_ = ((j >> 4) << 5) | (j & 15);
    else { int jm = j - half; np_ = ((jm >> 4) << 5) | 16 | (jm & 15); }
  } else np_ = j;
  bf16x4 o;
  o[0] = (bf16_t)tile[kk0][jj];     o[1] = (bf16_t)tile[kk0 + 1][jj];
  o[2] = (bf16_t)tile[kk0 + 2][jj]; o[3] = (bf16_t)tile[kk0 + 3][jj];
  *(bf16x4*)(d + (size_t)np_ * K + k0 + kk0) = o;
}

// ---------------- router ----------------
__global__ __launch_bounds__(256) void k_router(const float* __restrict__ x,
                                                const float* __restrict__ wg,
                                                int* __restrict__ counts,
                                                int* __restrict__ tki,
                                                float* __restrict__ tkp) {
  __shared__ float wgl[NE * D_EMB];
  int t = threadIdx.x;
  for (int i = t; i < NE * D_EMB; i += 256) {
    int dd = i >> 3, ee = i & 7;
    wgl[ee * D_EMB + dd] = wg[i];
  }
  __syncthreads();
  int wave = t >> 6, lane = t & 63;
  int tok = (blockIdx.x << 2) + wave;
  const float* xr = x + (size_t)tok * D_EMB;
  float acc[NE] = {};
  for (int d = lane; d < D_EMB; d += 64) {
    float xv = xr[d];
#pragma unroll
    for (int e = 0; e < NE; e++) acc[e] += xv * wgl[e * D_EMB + d];
  }
#pragma unroll
  for (int e = 0; e < NE; e++) {
#pragma unroll
    for (int off = 32; off; off >>= 1) acc[e] += __shfl_xor(acc[e], off);
  }
  if (lane == 0) {
    int i0 = 0; float s0 = acc[0];
#pragma unroll
    for (int e = 1; e < NE; e++) if (acc[e] > s0) { s0 = acc[e]; i0 = e; }
    int i1 = -1; float s1 = -3.4e38f;
#pragma unroll
    for (int e = 0; e < NE; e++) if (e != i0 && acc[e] > s1) { s1 = acc[e]; i1 = e; }
    float ex = __expf(s1 - s0);
    float inv = 1.f / (1.f + ex);
    tki[tok * 2] = i0; tki[tok * 2 + 1] = i1;
    tkp[tok * 2] = inv; tkp[tok * 2 + 1] = ex * inv;
    atomicAdd(&counts[i0], 1); atomicAdd(&counts[i1], 1);
  }
}

__global__ void k_offsets(const int* __restrict__ counts, int* __restrict__ offsets) {
  if (threadIdx.x == 0) {
    int s = 0;
#pragma unroll
    for (int e = 0; e < NE; e++) { offsets[e] = s; s += counts[e]; }
    offsets[NE] = s;
  }
}

__global__ __launch_bounds__(256) void k_scatter(const int* __restrict__ tki,
                                                 const float* __restrict__ tkp,
                                                 const int* __restrict__ offsets,
                                                 int* __restrict__ fill,
                                                 int* __restrict__ tlist,
                                                 int* __restrict__ tok2pos) {
  int tok = blockIdx.x * 256 + threadIdx.x;
  if (tok >= T_TOK) return;
#pragma unroll
  for (int k = 0; k < 2; k++) {
    int e = tki[tok * 2 + k];
    int pos = offsets[e] + atomicAdd(&fill[e], 1);
    tlist[pos] = tok;
    tok2pos[tok * 2 + k] = pos;
  }
}

// ============ grouped GEMM, 256x256 tile, BK=64, 8 waves (2Mx4N), phase-split ============
// T2 swizzle: byte_col ^= ((row&7)<<4) — 3-bit spread over all 32 banks (both-sides, rule #21).
// T3/T4 counted vmcnt(8) depth-2 pipeline, T5 setprio around MFMA clusters.
// PHASE 1: A = xb gathered by tlist [.,1024]; B = w12b[e] [4096][1024] (ILV); SwiGLU -> hb
// PHASE 2: A = hb contiguous [.,2048];       B = w3b[e]  [1024][2048];      -> partial
template <int PHASE>
__global__ __launch_bounds__(512, 2) void k_gemm8(const bf16_t* __restrict__ A,
                                                  const bf16_t* __restrict__ B,
                                                  const int* __restrict__ offsets,
                                                  const int* __restrict__ tlist,
                                                  bf16_t* __restrict__ hb,
                                                  float* __restrict__ partial) {
  constexpr int AK = (PHASE == 1) ? D_EMB : H_DIM;
  constexpr int NT = AK / 64;                        // K-tiles
  constexpr int BNT = (PHASE == 1) ? N1 : D_EMB;
  const int e = blockIdx.z;
  const int seg = offsets[e];
  const int cnt = offsets[e + 1] - seg;
  const int mt = blockIdx.y;
  if (mt * 256 >= cnt) return;
  const int n0 = blockIdx.x << 8;
  const bf16_t* Bexp = B + (size_t)e * (size_t)AK * BNT;

  __shared__ bf16_t As[2][256 * 64];   // 32 KB each buf, row stride 64 bf16 = 128 B
  __shared__ bf16_t Bs[2][256 * 64];

  const int tid = threadIdx.x;
  const int wave = tid >> 6, lane = tid & 63;
  const int wr = wave >> 2, wc = wave & 3;

  // ---- staging: LDS dest linear; global source carries the inverse swizzle.
  const bf16_t* srcA[4];
  const bf16_t* srcB[4];
#pragma unroll
  for (int i = 0; i < 4; i++) {
    int chunk = i * 512 + tid;          // 0..2047
    int row = chunk >> 3;               // 0..255
    int cphys = (chunk & 7) * 16;       // byte col in 128B row
    int clog = cphys ^ ((row & 7) << 4);
    int rb = mt * 256 + row;
    int rbc = (rb < cnt) ? rb : (cnt - 1);
    if (PHASE == 1) {
      int tok = tlist[seg + rbc];
      srcA[i] = A + (size_t)tok * AK + (clog >> 1);
    } else {
      srcA[i] = A + (size_t)(seg + rbc) * AK + (clog >> 1);
    }
    srcB[i] = Bexp + (size_t)(n0 + row) * AK + (clog >> 1);
  }

#define STAGE8(cur, kt)                                                        \
  {                                                                            \
    const int koff_ = (kt) * 64;                                               \
    _Pragma("unroll") for (int i_ = 0; i_ < 4; i_++)                           \
        gld_lds16(&As[cur][(i_ * 512 + wave * 64) * 8], srcA[i_] + koff_);     \
    _Pragma("unroll") for (int i_ = 0; i_ < 4; i_++)                           \
        gld_lds16(&Bs[cur][(i_ * 512 + wave * 64) * 8], srcB[i_] + koff_);     \
  }

  // ---- fragment read offsets (swizzled)
  const int fr = lane & 15;
  const int fkb = (lane >> 4) * 16;     // byte k-chunk within 32-k step
  int aoff[2][8], boff[2][4];
#pragma unroll
  for (int ks = 0; ks < 2; ks++) {
#pragma unroll
    for (int mf = 0; mf < 8; mf++) {
      int row = wr * 128 + mf * 16 + fr;
      int cl = ks * 64 + fkb;
      aoff[ks][mf] = row * 128 + (cl ^ ((row & 7) << 4));
    }
#pragma unroll
    for (int nf = 0; nf < 4; nf++) {
      int row = wc * 64 + nf * 16 + fr;
      int cl = ks * 64 + fkb;
      boff[ks][nf] = row * 128 + (cl ^ ((row & 7) << 4));
    }
  }

  f32x4 acc[8][4] = {};

#define DO_MFMA16(mh, ks)                                                      \
  __builtin_amdgcn_s_setprio(1);                                               \
  _Pragma("unroll") for (int i_ = 0; i_ < 4; i_++)                             \
  _Pragma("unroll") for (int nf_ = 0; nf_ < 4; nf_++)                          \
      acc[(mh) * 4 + i_][nf_] = __builtin_amdgcn_mfma_f32_16x16x32_bf16(       \
          afr[i_], bq[nf_], acc[(mh) * 4 + i_][nf_], 0, 0, 0);                 \
  __builtin_amdgcn_s_setprio(0);

  // prologue: stage tiles 0 and 1; wait tile 0 only (counted vmcnt)
  STAGE8(0, 0);
  STAGE8(1, 1);
  asm volatile("s_waitcnt vmcnt(8)" ::: "memory");
  __builtin_amdgcn_s_barrier();

  for (int t = 0; t < NT; ++t) {
    const int cur = t & 1;
    const char* asb = (const char*)&As[cur][0];
    const char* bsb = (const char*)&Bs[cur][0];
    bf16x8 afr[4], bq[4];

    // P0: ks0, m-half 0 (+ B ks0)
#pragma unroll
    for (int nf = 0; nf < 4; nf++) bq[nf] = *(const bf16x8*)(bsb + boff[0][nf]);
#pragma unroll
    for (int i = 0; i < 4; i++) afr[i] = *(const bf16x8*)(asb + aoff[0][i]);
    DO_MFMA16(0, 0);
    __builtin_amdgcn_sched_barrier(0);

    // P1: ks0, m-half 1
#pragma unroll
    for (int i = 0; i < 4; i++) afr[i] = *(const bf16x8*)(asb + aoff[0][4 + i]);
    DO_MFMA16(1, 0);
    __builtin_amdgcn_sched_barrier(0);

    // P2: ks1, m-half 0 (+ B ks1)
#pragma unroll
    for (int nf = 0; nf < 4; nf++) bq[nf] = *(const bf16x8*)(bsb + boff[1][nf]);
#pragma unroll
    for (int i = 0; i < 4; i++) afr[i] = *(const bf16x8*)(asb + aoff[1][i]);
    DO_MFMA16(0, 1);
    __builtin_amdgcn_sched_barrier(0);

    // P3: ks1, m-half 1 — reads, release buf[cur], prefetch t+2, MFMA, wait t+1
#pragma unroll
    for (int i = 0; i < 4; i++) afr[i] = *(const bf16x8*)(asb + aoff[1][4 + i]);
    __builtin_amdgcn_sched_barrier(0);
    asm volatile("s_waitcnt lgkmcnt(0)" ::: "memory");
    __builtin_amdgcn_s_barrier();          // all waves done reading buf[cur]
    if (t + 2 < NT) STAGE8(cur, t + 2);
    __builtin_amdgcn_sched_barrier(0);
    DO_MFMA16(1, 1);
    if (t + 2 < NT) {
      asm volatile("s_waitcnt vmcnt(8)" ::: "memory");   // tile t+1 landed
      __builtin_amdgcn_s_barrier();
    } else if (t + 1 < NT) {
      asm volatile("s_waitcnt vmcnt(0)" ::: "memory");   // last tile landed
      __builtin_amdgcn_s_barrier();
    }
    __builtin_amdgcn_sched_barrier(0);
  }

  // ---- epilogue ----
  if (PHASE == 1) {
#pragma unroll
    for (int mf = 0; mf < 8; mf++) {
      int rbase = mt * 256 + wr * 128 + mf * 16 + ((lane >> 4) << 2);
#pragma unroll
      for (int p = 0; p < 2; p++) {
        int hcol = (n0 >> 1) + wc * 32 + p * 16 + fr;
#pragma unroll
        for (int j = 0; j < 4; j++) {
          int r = rbase + j;
          if (r < cnt) {
            float g = acc[mf][2 * p][j];
            float v = acc[mf][2 * p + 1][j];
            float s = g / (1.f + __expf(-g));
            hb[(size_t)(seg + r) * H_DIM + hcol] = (bf16_t)(s * v);
          }
        }
      }
    }
  } else {
#pragma unroll
    for (int mf = 0; mf < 8; mf++) {
      int rbase = mt * 256 + wr * 128 + mf * 16 + ((lane >> 4) << 2);
#pragma unroll
      for (int j = 0; j < 4; j++) {
        int r = rbase + j;
        if (r < cnt) {
          float* op = partial + (size_t)(seg + r) * D_EMB + n0 + wc * 64 + fr;
#pragma unroll
          for (int nf = 0; nf < 4; nf++) op[nf * 16] = acc[mf][nf][j];
        }
      }
    }
  }
#undef STAGE8
#undef DO_MFMA16
}

// ---------------- combine: out[tok] = p0*partial[pos0] + p1*partial[pos1] ----------------
__global__ __launch_bounds__(256) void k_combine(const float* __restrict__ partial,
                                                 const float* __restrict__ tkp,
                                                 const int* __restrict__ tok2pos,
                                                 float* __restrict__ out) {
  int i = blockIdx.x * 256 + threadIdx.x;
  int tok = i >> 8;
  int c4 = i & 255;
  int p0 = tok2pos[tok * 2], p1 = tok2pos[tok * 2 + 1];
  float w0 = tkp[tok * 2], w1 = tkp[tok * 2 + 1];
  const float4* r0 = (const float4*)(partial + (size_t)p0 * D_EMB);
  const float4* r1 = (const float4*)(partial + (size_t)p1 * D_EMB);
  float4 a = r0[c4], b = r1[c4];
  float4 o;
  o.x = w0 * a.x + w1 * b.x;
  o.y = w0 * a.y + w1 * b.y;
  o.z = w0 * a.z + w1 * b.z;
  o.w = w0 * a.w + w1 * b.w;
  ((float4*)out)[i] = o;
}

extern "C" void kernel_launch(void* const* d_in, const int* in_sizes, int n_in,
                              void* d_out, int out_size, void* d_ws, size_t ws_size,
                              hipStream_t stream) {
  (void)in_sizes; (void)n_in; (void)ws_size; (void)out_size;
  const float* x   = (const float*)d_in[0];
  const float* w12 = (const float*)d_in[1];
  const float* w3  = (const float*)d_in[2];
  const float* wg  = (const float*)d_in[3];
  float* out = (float*)d_out;
  char* ws = (char*)d_ws;

  const size_t OFF_XB   = 0;                       // xb: 16 MiB
  const size_t OFF_W12B = 16777216;                // w12b: 64 MiB
  const size_t OFF_W3B  = OFF_W12B + 67108864;     // w3b: 32 MiB
  const size_t OFF_HB   = OFF_W3B + 33554432;      // hb: 64 MiB
  const size_t OFF_META = OFF_HB + 67108864;
  // partial (fp32 16384x1024 = 64 MiB) overlaps [xb|w12b] — dead by gemm2 time.
  const size_t OFF_PART = 0;

  bf16_t* xb   = (bf16_t*)(ws + OFF_XB);
  bf16_t* w12b = (bf16_t*)(ws + OFF_W12B);
  bf16_t* w3b  = (bf16_t*)(ws + OFF_W3B);
  bf16_t* hb   = (bf16_t*)(ws + OFF_HB);
  float* partial = (float*)(ws + OFF_PART);
  int*   counts  = (int*)(ws + OFF_META);
  int*   fill    = (int*)(ws + OFF_META + 32);
  int*   offsets = (int*)(ws + OFF_META + 64);
  int*   tki     = (int*)(ws + OFF_META + 128);
  float* tkp     = (float*)(ws + OFF_META + 128 + 65536);
  int*   tlist   = (int*)(ws + OFF_META + 128 + 2 * 65536);
  int*   tok2pos = (int*)(ws + OFF_META + 128 + 3 * 65536);

  hipMemsetAsync(ws + OFF_META, 0, 64, stream);

  k_cvt_x<<<4096, 256, 0, stream>>>(x, xb);
  k_cvt_w<true ><<<dim3(128, 32, 8), 256, 0, stream>>>(w12, w12b, D_EMB, N1);
  k_cvt_w<false><<<dim3(32, 64, 8), 256, 0, stream>>>(w3, w3b, H_DIM, D_EMB);
  k_router<<<2048, 256, 0, stream>>>(x, wg, counts, tki, tkp);
  k_offsets<<<1, 64, 0, stream>>>(counts, offsets);
  k_scatter<<<32, 256, 0, stream>>>(tki, tkp, offsets, fill, tlist, tok2pos);
  k_gemm8<1><<<dim3(16, 32, 8), 512, 0, stream>>>(xb, w12b, offsets, tlist, hb, nullptr);
  k_gemm8<2><<<dim3(4, 32, 8), 512, 0, stream>>>(hb, w3b, offsets, tlist, nullptr, partial);
  k_combine<<<T_TOK, 256, 0, stream>>>(partial, tkp, tok2pos, out);
}

// Round 5
// 441.703 us; speedup vs baseline: 1.5676x; 1.5068x over previous
//
#include <hip/hip_runtime.h>
#include <hip/hip_bf16.h>
#include <stdint.h>

#define T_TOK 8192
#define D_EMB 1024
#define H_DIM 2048
#define N1 4096
#define NE 8
#define RBLK 256   // router blocks; 32 tokens each

typedef __bf16 bf16_t;
typedef __bf16 bf16x8 __attribute__((ext_vector_type(8)));
typedef __bf16 bf16x4 __attribute__((ext_vector_type(4)));
typedef float f32x4 __attribute__((ext_vector_type(4)));

typedef __attribute__((address_space(1))) void gvoid_t;
typedef __attribute__((address_space(3))) void svoid_t;

__device__ __forceinline__ void gld_lds16(bf16_t* lds, const bf16_t* g) {
  __builtin_amdgcn_global_load_lds((gvoid_t*)g, (svoid_t*)lds, 16, 0, 0);
}

// ---------------- x fp32 -> bf16 ----------------
__global__ __launch_bounds__(256) void k_cvt_x(const float* __restrict__ x,
                                               bf16_t* __restrict__ xb) {
  int i = blockIdx.x * 256 + threadIdx.x;
  const float4* p = (const float4*)x;
  float4 a = p[i * 2], b = p[i * 2 + 1];
  bf16x8 o;
  o[0] = (bf16_t)a.x; o[1] = (bf16_t)a.y; o[2] = (bf16_t)a.z; o[3] = (bf16_t)a.w;
  o[4] = (bf16_t)b.x; o[5] = (bf16_t)b.y; o[6] = (bf16_t)b.z; o[7] = (bf16_t)b.w;
  *(bf16x8*)(xb + (size_t)i * 8) = o;
}

// ------- weight convert: [E][K][N] fp32 -> [E][N'][K] bf16 (transpose, opt interleave) -------
template <bool ILV>
__global__ __launch_bounds__(256) void k_cvt_w(const float* __restrict__ src,
                                               bf16_t* __restrict__ dst, int K, int N) {
  __shared__ float tile[32][33];
  int e = blockIdx.z;
  int k0 = blockIdx.y << 5, j0 = blockIdx.x << 5;
  const float* s = src + (size_t)e * K * N;
  bf16_t* d = dst + (size_t)e * K * N;
  int t = threadIdx.x;
  int col = t & 31, r0 = t >> 5;
#pragma unroll
  for (int i = 0; i < 4; i++)
    tile[r0 + i * 8][col] = s[(size_t)(k0 + r0 + i * 8) * N + j0 + col];
  __syncthreads();
  int jj = t >> 3, kk0 = (t & 7) << 2;
  int j = j0 + jj, np_;
  if (ILV) {
    int half = N >> 1;
    if (j < half) np_ = ((j >> 4) << 5) | (j & 15);
    else { int jm = j - half; np_ = ((jm >> 4) << 5) | 16 | (jm & 15); }
  } else np_ = j;
  bf16x4 o;
  o[0] = (bf16_t)tile[kk0][jj];     o[1] = (bf16_t)tile[kk0 + 1][jj];
  o[2] = (bf16_t)tile[kk0 + 2][jj]; o[3] = (bf16_t)tile[kk0 + 3][jj];
  *(bf16x4*)(d + (size_t)np_ * K + k0 + kk0) = o;
}

// ---------------- router: scores, top-2, softmax, per-block histogram (NO global atomics) ----
__global__ __launch_bounds__(256) void k_router(const float* __restrict__ x,
                                                const float* __restrict__ wg,
                                                int* __restrict__ tki,
                                                float* __restrict__ tkp,
                                                int* __restrict__ blockhist) {
  __shared__ float wgl[NE * D_EMB];  // [e][d]
  __shared__ int hist[NE];
  int t = threadIdx.x;
  if (t < NE) hist[t] = 0;
  // conflict-free LDS writes (dest linear in t); src wg[d][e] small + L2-resident
  for (int i = t; i < NE * D_EMB; i += 256) {
    int e = i >> 10, d = i & 1023;
    wgl[i] = wg[d * NE + e];
  }
  __syncthreads();
  int wave = t >> 6, lane = t & 63;
#pragma unroll
  for (int it = 0; it < 8; it++) {
    int tok = blockIdx.x * 32 + wave * 8 + it;
    const float* xr = x + (size_t)tok * D_EMB;
    float acc[NE] = {};
    for (int d = lane; d < D_EMB; d += 64) {
      float xv = xr[d];
#pragma unroll
      for (int e = 0; e < NE; e++) acc[e] += xv * wgl[e * D_EMB + d];
    }
#pragma unroll
    for (int e = 0; e < NE; e++) {
#pragma unroll
      for (int off = 32; off; off >>= 1) acc[e] += __shfl_xor(acc[e], off);
    }
    if (lane == 0) {
      int i0 = 0; float s0 = acc[0];
#pragma unroll
      for (int e = 1; e < NE; e++) if (acc[e] > s0) { s0 = acc[e]; i0 = e; }
      int i1 = -1; float s1 = -3.4e38f;
#pragma unroll
      for (int e = 0; e < NE; e++) if (e != i0 && acc[e] > s1) { s1 = acc[e]; i1 = e; }
      float ex = __expf(s1 - s0);
      float inv = 1.f / (1.f + ex);
      tki[tok * 2] = i0; tki[tok * 2 + 1] = i1;
      tkp[tok * 2] = inv; tkp[tok * 2 + 1] = ex * inv;
      atomicAdd(&hist[i0], 1); atomicAdd(&hist[i1], 1);  // LDS only
    }
  }
  __syncthreads();
  if (t < NE) blockhist[blockIdx.x * NE + t] = hist[t];
}

// ---------------- offsets + per-block bases (serial, deterministic) ----------------
__global__ __launch_bounds__(64) void k_offsets(const int* __restrict__ bh,
                                                int* __restrict__ bb,
                                                int* __restrict__ offsets) {
  __shared__ int csum[NE];
  __shared__ int soff[NE + 1];
  int e = threadIdx.x;
  if (e < NE) {
    int s = 0;
    for (int b = 0; b < RBLK; b++) s += bh[b * NE + e];
    csum[e] = s;
  }
  __syncthreads();
  if (e == 0) {
    int s = 0;
#pragma unroll
    for (int i = 0; i < NE; i++) { soff[i] = s; s += csum[i]; }
    soff[NE] = s;
#pragma unroll
    for (int i = 0; i <= NE; i++) offsets[i] = soff[i];
  }
  __syncthreads();
  if (e < NE) {
    int s = soff[e];
    for (int b = 0; b < RBLK; b++) { bb[b * NE + e] = s; s += bh[b * NE + e]; }
  }
}

// ---------------- scatter: LDS-rank + blockbase (no global atomics) ----------------
__global__ __launch_bounds__(64) void k_scatter(const int* __restrict__ tki,
                                                const int* __restrict__ bb,
                                                int* __restrict__ tlist,
                                                int* __restrict__ tok2pos) {
  __shared__ int lh[NE];
  int t = threadIdx.x;
  if (t < NE) lh[t] = 0;
  __syncthreads();
  if (t < 32) {
    int tok = blockIdx.x * 32 + t;
#pragma unroll
    for (int k = 0; k < 2; k++) {
      int e = tki[tok * 2 + k];
      int r = atomicAdd(&lh[e], 1);
      int pos = bb[blockIdx.x * NE + e] + r;
      tlist[pos] = tok;
      tok2pos[tok * 2 + k] = pos;
    }
  }
}

// ============ grouped GEMM, 256x256 tile, BK=64, 8 waves (2Mx4N), phase-split ============
// T2 swizzle: byte_col ^= ((row&7)<<4) (both-sides, rule #21).
// T3/T4 counted vmcnt(8) depth-2 pipeline, T5 setprio around MFMA clusters.
template <int PHASE>
__global__ __launch_bounds__(512, 2) void k_gemm8(const bf16_t* __restrict__ A,
                                                  const bf16_t* __restrict__ B,
                                                  const int* __restrict__ offsets,
                                                  const int* __restrict__ tlist,
                                                  bf16_t* __restrict__ hb,
                                                  float* __restrict__ partial) {
  constexpr int AK = (PHASE == 1) ? D_EMB : H_DIM;
  constexpr int NT = AK / 64;
  constexpr int BNT = (PHASE == 1) ? N1 : D_EMB;
  const int e = blockIdx.z;
  const int seg = offsets[e];
  const int cnt = offsets[e + 1] - seg;
  const int mt = blockIdx.y;
  if (mt * 256 >= cnt) return;
  const int n0 = blockIdx.x << 8;
  const bf16_t* Bexp = B + (size_t)e * (size_t)AK * BNT;

  __shared__ bf16_t As[2][256 * 64];
  __shared__ bf16_t Bs[2][256 * 64];

  const int tid = threadIdx.x;
  const int wave = tid >> 6, lane = tid & 63;
  const int wr = wave >> 2, wc = wave & 3;

  const bf16_t* srcA[4];
  const bf16_t* srcB[4];
#pragma unroll
  for (int i = 0; i < 4; i++) {
    int chunk = i * 512 + tid;
    int row = chunk >> 3;
    int cphys = (chunk & 7) * 16;
    int clog = cphys ^ ((row & 7) << 4);
    int rb = mt * 256 + row;
    int rbc = (rb < cnt) ? rb : (cnt - 1);
    if (PHASE == 1) {
      int tok = tlist[seg + rbc];
      srcA[i] = A + (size_t)tok * AK + (clog >> 1);
    } else {
      srcA[i] = A + (size_t)(seg + rbc) * AK + (clog >> 1);
    }
    srcB[i] = Bexp + (size_t)(n0 + row) * AK + (clog >> 1);
  }

#define STAGE8(cur, kt)                                                        \
  {                                                                            \
    const int koff_ = (kt) * 64;                                               \
    _Pragma("unroll") for (int i_ = 0; i_ < 4; i_++)                           \
        gld_lds16(&As[cur][(i_ * 512 + wave * 64) * 8], srcA[i_] + koff_);     \
    _Pragma("unroll") for (int i_ = 0; i_ < 4; i_++)                           \
        gld_lds16(&Bs[cur][(i_ * 512 + wave * 64) * 8], srcB[i_] + koff_);     \
  }

  const int fr = lane & 15;
  const int fkb = (lane >> 4) * 16;
  int aoff[2][8], boff[2][4];
#pragma unroll
  for (int ks = 0; ks < 2; ks++) {
#pragma unroll
    for (int mf = 0; mf < 8; mf++) {
      int row = wr * 128 + mf * 16 + fr;
      int cl = ks * 64 + fkb;
      aoff[ks][mf] = row * 128 + (cl ^ ((row & 7) << 4));
    }
#pragma unroll
    for (int nf = 0; nf < 4; nf++) {
      int row = wc * 64 + nf * 16 + fr;
      int cl = ks * 64 + fkb;
      boff[ks][nf] = row * 128 + (cl ^ ((row & 7) << 4));
    }
  }

  f32x4 acc[8][4] = {};

#define DO_MFMA16(mh, ks)                                                      \
  __builtin_amdgcn_s_setprio(1);                                               \
  _Pragma("unroll") for (int i_ = 0; i_ < 4; i_++)                             \
  _Pragma("unroll") for (int nf_ = 0; nf_ < 4; nf_++)                          \
      acc[(mh) * 4 + i_][nf_] = __builtin_amdgcn_mfma_f32_16x16x32_bf16(       \
          afr[i_], bq[nf_], acc[(mh) * 4 + i_][nf_], 0, 0, 0);                 \
  __builtin_amdgcn_s_setprio(0);

  STAGE8(0, 0);
  STAGE8(1, 1);
  asm volatile("s_waitcnt vmcnt(8)" ::: "memory");
  __builtin_amdgcn_s_barrier();

  for (int t = 0; t < NT; ++t) {
    const int cur = t & 1;
    const char* asb = (const char*)&As[cur][0];
    const char* bsb = (const char*)&Bs[cur][0];
    bf16x8 afr[4], bq[4];

#pragma unroll
    for (int nf = 0; nf < 4; nf++) bq[nf] = *(const bf16x8*)(bsb + boff[0][nf]);
#pragma unroll
    for (int i = 0; i < 4; i++) afr[i] = *(const bf16x8*)(asb + aoff[0][i]);
    DO_MFMA16(0, 0);
    __builtin_amdgcn_sched_barrier(0);

#pragma unroll
    for (int i = 0; i < 4; i++) afr[i] = *(const bf16x8*)(asb + aoff[0][4 + i]);
    DO_MFMA16(1, 0);
    __builtin_amdgcn_sched_barrier(0);

#pragma unroll
    for (int nf = 0; nf < 4; nf++) bq[nf] = *(const bf16x8*)(bsb + boff[1][nf]);
#pragma unroll
    for (int i = 0; i < 4; i++) afr[i] = *(const bf16x8*)(asb + aoff[1][i]);
    DO_MFMA16(0, 1);
    __builtin_amdgcn_sched_barrier(0);

#pragma unroll
    for (int i = 0; i < 4; i++) afr[i] = *(const bf16x8*)(asb + aoff[1][4 + i]);
    __builtin_amdgcn_sched_barrier(0);
    asm volatile("s_waitcnt lgkmcnt(0)" ::: "memory");
    __builtin_amdgcn_s_barrier();
    if (t + 2 < NT) STAGE8(cur, t + 2);
    __builtin_amdgcn_sched_barrier(0);
    DO_MFMA16(1, 1);
    if (t + 2 < NT) {
      asm volatile("s_waitcnt vmcnt(8)" ::: "memory");
      __builtin_amdgcn_s_barrier();
    } else if (t + 1 < NT) {
      asm volatile("s_waitcnt vmcnt(0)" ::: "memory");
      __builtin_amdgcn_s_barrier();
    }
    __builtin_amdgcn_sched_barrier(0);
  }

  if (PHASE == 1) {
#pragma unroll
    for (int mf = 0; mf < 8; mf++) {
      int rbase = mt * 256 + wr * 128 + mf * 16 + ((lane >> 4) << 2);
#pragma unroll
      for (int p = 0; p < 2; p++) {
        int hcol = (n0 >> 1) + wc * 32 + p * 16 + fr;
#pragma unroll
        for (int j = 0; j < 4; j++) {
          int r = rbase + j;
          if (r < cnt) {
            float g = acc[mf][2 * p][j];
            float v = acc[mf][2 * p + 1][j];
            float s = g / (1.f + __expf(-g));
            hb[(size_t)(seg + r) * H_DIM + hcol] = (bf16_t)(s * v);
          }
        }
      }
    }
  } else {
#pragma unroll
    for (int mf = 0; mf < 8; mf++) {
      int rbase = mt * 256 + wr * 128 + mf * 16 + ((lane >> 4) << 2);
#pragma unroll
      for (int j = 0; j < 4; j++) {
        int r = rbase + j;
        if (r < cnt) {
          float* op = partial + (size_t)(seg + r) * D_EMB + n0 + wc * 64 + fr;
#pragma unroll
          for (int nf = 0; nf < 4; nf++) op[nf * 16] = acc[mf][nf][j];
        }
      }
    }
  }
#undef STAGE8
#undef DO_MFMA16
}

// ---------------- combine: out[tok] = p0*partial[pos0] + p1*partial[pos1] ----------------
__global__ __launch_bounds__(256) void k_combine(const float* __restrict__ partial,
                                                 const float* __restrict__ tkp,
                                                 const int* __restrict__ tok2pos,
                                                 float* __restrict__ out) {
  int i = blockIdx.x * 256 + threadIdx.x;
  int tok = i >> 8;
  int c4 = i & 255;
  int p0 = tok2pos[tok * 2], p1 = tok2pos[tok * 2 + 1];
  float w0 = tkp[tok * 2], w1 = tkp[tok * 2 + 1];
  const float4* r0 = (const float4*)(partial + (size_t)p0 * D_EMB);
  const float4* r1 = (const float4*)(partial + (size_t)p1 * D_EMB);
  float4 a = r0[c4], b = r1[c4];
  float4 o;
  o.x = w0 * a.x + w1 * b.x;
  o.y = w0 * a.y + w1 * b.y;
  o.z = w0 * a.z + w1 * b.z;
  o.w = w0 * a.w + w1 * b.w;
  ((float4*)out)[i] = o;
}

extern "C" void kernel_launch(void* const* d_in, const int* in_sizes, int n_in,
                              void* d_out, int out_size, void* d_ws, size_t ws_size,
                              hipStream_t stream) {
  (void)in_sizes; (void)n_in; (void)ws_size; (void)out_size;
  const float* x   = (const float*)d_in[0];
  const float* w12 = (const float*)d_in[1];
  const float* w3  = (const float*)d_in[2];
  const float* wg  = (const float*)d_in[3];
  float* out = (float*)d_out;
  char* ws = (char*)d_ws;

  const size_t OFF_XB   = 0;                       // xb: 16 MiB
  const size_t OFF_W12B = 16777216;                // w12b: 64 MiB
  const size_t OFF_W3B  = OFF_W12B + 67108864;     // w3b: 32 MiB
  const size_t OFF_HB   = OFF_W3B + 33554432;      // hb: 64 MiB
  const size_t OFF_META = OFF_HB + 67108864;
  // partial (fp32 16384x1024 = 64 MiB) overlaps [xb|w12b] — dead by gemm2 time.
  const size_t OFF_PART = 0;

  bf16_t* xb   = (bf16_t*)(ws + OFF_XB);
  bf16_t* w12b = (bf16_t*)(ws + OFF_W12B);
  bf16_t* w3b  = (bf16_t*)(ws + OFF_W3B);
  bf16_t* hb   = (bf16_t*)(ws + OFF_HB);
  float* partial = (float*)(ws + OFF_PART);
  int*   offsets   = (int*)(ws + OFF_META);                 // 64 B
  int*   blockhist = (int*)(ws + OFF_META + 64);            // 8 KiB
  int*   blockbase = (int*)(ws + OFF_META + 64 + 8192);     // 8 KiB
  int*   tki       = (int*)(ws + OFF_META + 32768);
  float* tkp       = (float*)(ws + OFF_META + 32768 + 65536);
  int*   tlist     = (int*)(ws + OFF_META + 32768 + 2 * 65536);
  int*   tok2pos   = (int*)(ws + OFF_META + 32768 + 3 * 65536);

  k_cvt_x<<<4096, 256, 0, stream>>>(x, xb);
  k_cvt_w<true ><<<dim3(128, 32, 8), 256, 0, stream>>>(w12, w12b, D_EMB, N1);
  k_cvt_w<false><<<dim3(32, 64, 8), 256, 0, stream>>>(w3, w3b, H_DIM, D_EMB);
  k_router<<<RBLK, 256, 0, stream>>>(x, wg, tki, tkp, blockhist);
  k_offsets<<<1, 64, 0, stream>>>(blockhist, blockbase, offsets);
  k_scatter<<<RBLK, 64, 0, stream>>>(tki, blockbase, tlist, tok2pos);
  k_gemm8<1><<<dim3(16, 32, 8), 512, 0, stream>>>(xb, w12b, offsets, tlist, hb, nullptr);
  k_gemm8<2><<<dim3(4, 32, 8), 512, 0, stream>>>(hb, w3b, offsets, tlist, nullptr, partial);
  k_combine<<<T_TOK, 256, 0, stream>>>(partial, tkp, tok2pos, out);
}